// Round 10
// baseline (354.244 us; speedup 1.0000x reference)
//
#include <hip/hip_runtime.h>
#include <hip/hip_fp16.h>

#define N_NODES 50000
#define N_EDGES 1600000
#define IN_F 256
#define NEG_SLOPE 0.2f
#define CHUNK 1024
#define NCH ((N_NODES + CHUNK - 1) / CHUNK)   // 49
#define NPAD 50048                             // padded node stride for deg8/off8
#define NCOPY 8
#define EPB 2048                               // edges per block in deg/sortp (MUST match)
#define NEB ((N_EDGES + EPB - 1) / EPB)        // 782 blocks

typedef _Float16 f16x8 __attribute__((ext_vector_type(8)));
typedef float f32x4 __attribute__((ext_vector_type(4)));

// ---- K1: ft16 = half(feat @ W) via MFMA f16 + fused el/er -------------------
__global__ __launch_bounds__(256) void k_gemm(const float* __restrict__ feat,
                                              const float* __restrict__ W,
                                              const float* __restrict__ attn_l,
                                              const float* __restrict__ attn_r,
                                              __half* __restrict__ ft16,
                                              float* __restrict__ el,
                                              float* __restrict__ er) {
  __shared__ __align__(16) _Float16 Wt[4 * 128 * 8];   // 8 KB
  __shared__ __align__(16) _Float16 Fl[64 * 40];       // 5 KB (pad 32->40)
  const int tid = threadIdx.x;
  const int lane = tid & 63;
  const int w = tid >> 6;          // wave 0..3
  const int c0 = lane & 15;        // col-in-tile
  const int g = lane >> 4;         // k-subgroup 0..3
  const int row0 = blockIdx.x * 64;

  f32x4 acc[8];
#pragma unroll
  for (int t = 0; t < 8; ++t) acc[t] = f32x4{0.f, 0.f, 0.f, 0.f};

  const int fr = tid >> 2;               // feat row 0..63
  const int fk = (tid & 3) * 8;          // feat k-slot
  const int wc = tid & 127;              // W col 0..127
  const int wgp = tid >> 7;              // W g-pair 0/1

  for (int kt = 0; kt < IN_F; kt += 32) {
    __syncthreads();
    {
      int grow = row0 + fr;
      if (grow >= N_NODES) grow = N_NODES - 1;   // clamp; epilogue guarded
      const float* fp = feat + (size_t)grow * IN_F + kt + fk;
      float4 v0 = *(const float4*)fp;
      float4 v1 = *(const float4*)(fp + 4);
      f16x8 h;
      h[0] = (_Float16)v0.x; h[1] = (_Float16)v0.y;
      h[2] = (_Float16)v0.z; h[3] = (_Float16)v0.w;
      h[4] = (_Float16)v1.x; h[5] = (_Float16)v1.y;
      h[6] = (_Float16)v1.z; h[7] = (_Float16)v1.w;
      *(f16x8*)&Fl[fr * 40 + fk] = h;
    }
#pragma unroll
    for (int gg = 0; gg < 2; ++gg) {
      int gw = wgp * 2 + gg;
      f16x8 h;
#pragma unroll
      for (int j = 0; j < 8; ++j)
        h[j] = (_Float16)W[(size_t)(kt + gw * 8 + j) * 128 + wc];
      *(f16x8*)&Wt[(gw * 128 + wc) * 8] = h;
    }
    __syncthreads();
    f16x8 a = *(const f16x8*)&Fl[(w * 16 + c0) * 40 + g * 8];
#pragma unroll
    for (int t = 0; t < 8; ++t) {
      f16x8 b = *(const f16x8*)&Wt[(g * 128 + t * 16 + c0) * 8];
      acc[t] = __builtin_amdgcn_mfma_f32_16x16x32_f16(a, b, acc[t], 0, 0, 0);
    }
  }

  float al8[8], ar8[8];
#pragma unroll
  for (int t = 0; t < 8; ++t) {
    al8[t] = attn_l[t * 16 + c0];
    ar8[t] = attn_r[t * 16 + c0];
  }
#pragma unroll
  for (int r = 0; r < 4; ++r) {
    int row = row0 + w * 16 + g * 4 + r;
    float sl0 = 0.f, sl1 = 0.f, sr0 = 0.f, sr1 = 0.f;
#pragma unroll
    for (int t = 0; t < 4; ++t) {
      sl0 = fmaf(acc[t][r], al8[t], sl0);
      sr0 = fmaf(acc[t][r], ar8[t], sr0);
    }
#pragma unroll
    for (int t = 4; t < 8; ++t) {
      sl1 = fmaf(acc[t][r], al8[t], sl1);
      sr1 = fmaf(acc[t][r], ar8[t], sr1);
    }
#pragma unroll
    for (int m = 1; m < 16; m <<= 1) {
      sl0 += __shfl_xor(sl0, m, 64);
      sl1 += __shfl_xor(sl1, m, 64);
      sr0 += __shfl_xor(sr0, m, 64);
      sr1 += __shfl_xor(sr1, m, 64);
    }
    if (row < N_NODES) {
#pragma unroll
      for (int t = 0; t < 8; ++t)
        ft16[(size_t)row * 128 + t * 16 + c0] = __float2half(acc[t][r]);
      if (c0 == 0) {
        el[row * 2 + 0] = sl0; el[row * 2 + 1] = sl1;
        er[row * 2 + 0] = sr0; er[row * 2 + 1] = sr1;
      }
    }
  }
}

// ---- K2: fire-and-forget 8-way privatized histogram (no return use) ---------
// Block geometry MUST match k_sortp: EPB edges/block, copy = blockIdx&7.
__global__ __launch_bounds__(256) void k_deg(const int* __restrict__ dst,
                                             int* __restrict__ deg8) {
  int* mydeg = deg8 + (blockIdx.x & 7) * NPAD;
  int base4 = blockIdx.x * (EPB / 4) + threadIdx.x;   // int4 index
#pragma unroll
  for (int h = 0; h < 2; ++h) {
    int i4 = base4 + h * 256;
    if (i4 < N_EDGES / 4) {
      int4 d4 = ((const int4*)dst)[i4];
      atomicAdd(&mydeg[d4.x], 1);
      atomicAdd(&mydeg[d4.y], 1);
      atomicAdd(&mydeg[d4.z], 1);
      atomicAdd(&mydeg[d4.w], 1);
    }
  }
}

// ---- K3a/b/c: chunked exclusive scan over summed degrees --------------------
__global__ __launch_bounds__(256) void k_scanA(const int* __restrict__ deg8,
                                               int* __restrict__ csum) {
  __shared__ int ws[4];
  int b = blockIdx.x, tid = threadIdx.x, lane = tid & 63, w = tid >> 6;
  int i0 = b * CHUNK + tid * 4;
  int s = 0;
#pragma unroll
  for (int c = 0; c < NCOPY; ++c) {
    const int* dp = deg8 + c * NPAD;
#pragma unroll
    for (int j = 0; j < 4; ++j) {
      int i = i0 + j;
      if (i < N_NODES) s += dp[i];
    }
  }
#pragma unroll
  for (int m = 32; m > 0; m >>= 1) s += __shfl_xor(s, m, 64);
  if (lane == 0) ws[w] = s;
  __syncthreads();
  if (tid == 0) csum[b] = ws[0] + ws[1] + ws[2] + ws[3];
}

__global__ void k_scanB(const int* __restrict__ csum, int* __restrict__ coff,
                        int* __restrict__ rowptr) {
  int tid = threadIdx.x;                  // 64 threads
  int v = (tid < NCH) ? csum[tid] : 0;
  int x = v;
#pragma unroll
  for (int off = 1; off < 64; off <<= 1) {
    int y = __shfl_up(x, off, 64);
    if (tid >= off) x += y;
  }
  if (tid < NCH) coff[tid] = x - v;
  if (tid == NCH - 1) rowptr[N_NODES] = x;
}

// scanC: writes rowptr AND the per-copy cursor array off8 (consumed by sortp).
__global__ __launch_bounds__(256) void k_scanC(const int* __restrict__ deg8,
                                               const int* __restrict__ coff,
                                               int* __restrict__ rowptr,
                                               int* __restrict__ off8) {
  __shared__ int wtot[4];
  int b = blockIdx.x, tid = threadIdx.x, lane = tid & 63, w = tid >> 6;
  int i0 = b * CHUNK + tid * 4;
  int dc[NCOPY][4];
  int d[4] = {0, 0, 0, 0};
#pragma unroll
  for (int c = 0; c < NCOPY; ++c) {
    const int* dp = deg8 + c * NPAD;
#pragma unroll
    for (int j = 0; j < 4; ++j) {
      int v = (i0 + j < N_NODES) ? dp[i0 + j] : 0;
      dc[c][j] = v;
      d[j] += v;
    }
  }
  int t1 = d[0] + d[1], t2 = t1 + d[2], t3 = t2 + d[3];
  int x = t3;
#pragma unroll
  for (int off = 1; off < 64; off <<= 1) {
    int y = __shfl_up(x, off, 64);
    if (lane >= off) x += y;
  }
  if (lane == 63) wtot[w] = x;
  __syncthreads();
  int woff = 0;
  for (int j = 0; j < w; ++j) woff += wtot[j];
  int excl = coff[b] + woff + (x - t3);
  int pre[4] = {0, d[0], t1, t2};
#pragma unroll
  for (int j = 0; j < 4; ++j) {
    int i = i0 + j;
    if (i < N_NODES) {
      int run = excl + pre[j];
      rowptr[i] = run;
#pragma unroll
      for (int c = 0; c < NCOPY; ++c) {
        off8[c * NPAD + i] = run;
        run += dc[c][j];
      }
    }
  }
}

// ---- K4: counting-sort; position from privatized cursor atomic --------------
// Same geometry as k_deg so per-copy counts match exactly.
__device__ __forceinline__ void sort1(int s, int d,
                                      int* __restrict__ mycur,
                                      const float2* __restrict__ el2,
                                      const float2* __restrict__ er2,
                                      unsigned long long* __restrict__ rec) {
  float2 a = el2[s];
  float2 b = er2[d];
  float e0 = a.x + b.x, e1 = a.y + b.y;
  e0 = e0 > 0.f ? e0 : NEG_SLOPE * e0;
  e1 = e1 > 0.f ? e1 : NEG_SLOPE * e1;
  __half2 h = __floats2half2_rn(__expf(e0), __expf(e1));
  unsigned long long v =
      ((unsigned long long)(*(unsigned*)&h) << 32) | (unsigned)s;
  int pos = atomicAdd(&mycur[d], 1);
  __builtin_nontemporal_store(v, &rec[pos]);
}

__global__ __launch_bounds__(256) void k_sortp(const int* __restrict__ src,
                                               const int* __restrict__ dst,
                                               int* __restrict__ off8,
                                               const float2* __restrict__ el2,
                                               const float2* __restrict__ er2,
                                               unsigned long long* __restrict__ rec) {
  int* mycur = off8 + (blockIdx.x & 7) * NPAD;
  int base4 = blockIdx.x * (EPB / 4) + threadIdx.x;   // int4 index
#pragma unroll
  for (int h = 0; h < 2; ++h) {
    int i4 = base4 + h * 256;
    if (i4 < N_EDGES / 4) {
      int4 s4 = ((const int4*)src)[i4];
      int4 d4 = ((const int4*)dst)[i4];
      sort1(s4.x, d4.x, mycur, el2, er2, rec);
      sort1(s4.y, d4.y, mycur, el2, er2, rec);
      sort1(s4.z, d4.z, mycur, el2, er2, rec);
      sort1(s4.w, d4.w, mycur, el2, er2, rec);
    }
  }
}

// ---- K5: aggregation, wave per node, unroll x8, fused softmax normalize -----
__global__ __launch_bounds__(256) void k_agg(const unsigned long long* __restrict__ rec,
                                             const int* __restrict__ rowptr,
                                             const __half2* __restrict__ ft2,
                                             float2* __restrict__ out) {
  int t = blockIdx.x * 256 + threadIdx.x;
  int node = t >> 6, lane = t & 63;
  if (node >= N_NODES) return;
  int beg = rowptr[node], end = rowptr[node + 1];
  bool h1 = lane >= 32;                 // lanes 0-31: head0 feats, 32-63: head1
  float ax = 0.f, ay = 0.f, s = 0.f;
  int i = beg;
  for (; i + 8 <= end; i += 8) {
    unsigned long long r[8];
#pragma unroll
    for (int j = 0; j < 8; ++j) r[j] = __builtin_nontemporal_load(&rec[i + j]);
    __half2 f[8];
#pragma unroll
    for (int j = 0; j < 8; ++j)
      f[j] = ft2[(size_t)(unsigned)(r[j] & 0xffffffffu) * 64 + lane];
#pragma unroll
    for (int j = 0; j < 8; ++j) {
      unsigned pw = (unsigned)(r[j] >> 32);
      float2 p = __half22float2(*(const __half2*)&pw);
      float a = h1 ? p.y : p.x;
      float2 g = __half22float2(f[j]);
      ax = fmaf(a, g.x, ax); ay = fmaf(a, g.y, ay);
      s += a;
    }
  }
  for (; i < end; ++i) {
    unsigned long long r = rec[i];
    unsigned pw = (unsigned)(r >> 32);
    float2 p = __half22float2(*(const __half2*)&pw);
    float a = h1 ? p.y : p.x;
    float2 g = __half22float2(ft2[(size_t)(unsigned)(r & 0xffffffffu) * 64 + lane]);
    ax = fmaf(a, g.x, ax); ay = fmaf(a, g.y, ay);
    s += a;
  }
  float inv = 1.f / fmaxf(s, 1e-20f);
  out[(size_t)node * 64 + lane] = make_float2(ax * inv, ay * inv);
}

extern "C" void kernel_launch(void* const* d_in, const int* in_sizes, int n_in,
                              void* d_out, int out_size, void* d_ws, size_t ws_size,
                              hipStream_t stream) {
  const float* feat   = (const float*)d_in[0];
  const int*   src    = (const int*)d_in[1];
  const int*   dst    = (const int*)d_in[2];
  const float* W      = (const float*)d_in[3];
  const float* attn_l = (const float*)d_in[4];
  const float* attn_r = (const float*)d_in[5];
  float* out = (float*)d_out;

  char* base = (char*)d_ws;
  size_t off = 0;
  auto bump = [&](size_t bytes) -> void* {
    void* p = base + off;
    off = (off + bytes + 255) & ~(size_t)255;
    return p;
  };
  __half* ft16   = (__half*)bump(sizeof(__half) * N_NODES * 128);  // 12.8 MB
  float*  el     = (float*)bump(sizeof(float) * N_NODES * 2);
  float*  er     = (float*)bump(sizeof(float) * N_NODES * 2);
  int*    deg8   = (int*)bump(sizeof(int) * NCOPY * NPAD);         // 1.6 MB
  int*    off8   = (int*)bump(sizeof(int) * NCOPY * NPAD);         // 1.6 MB
  int*    csum   = (int*)bump(sizeof(int) * NCH);
  int*    coff   = (int*)bump(sizeof(int) * NCH);
  int*    rowptr = (int*)bump(sizeof(int) * (N_NODES + 1));
  unsigned long long* rec =
      (unsigned long long*)bump(sizeof(unsigned long long) * N_EDGES); // 12.8 MB
  (void)ws_size; (void)in_sizes; (void)n_in; (void)out_size;

  (void)hipMemsetAsync(deg8, 0, sizeof(int) * NCOPY * NPAD, stream);

  k_deg<<<NEB, 256, 0, stream>>>(dst, deg8);
  k_gemm<<<(N_NODES + 63) / 64, 256, 0, stream>>>(feat, W, attn_l, attn_r, ft16, el, er);
  k_scanA<<<NCH, 256, 0, stream>>>(deg8, csum);
  k_scanB<<<1, 64, 0, stream>>>(csum, coff, rowptr);
  k_scanC<<<NCH, 256, 0, stream>>>(deg8, coff, rowptr, off8);
  k_sortp<<<NEB, 256, 0, stream>>>(src, dst, off8,
      (const float2*)el, (const float2*)er, rec);
  k_agg<<<(N_NODES * 64 + 255) / 256, 256, 0, stream>>>(rec, rowptr,
      (const __half2*)ft16, (float2*)out);
}